// Round 5
// baseline (816.980 us; speedup 1.0000x reference)
//
#include <hip/hip_runtime.h>
#include <hip/hip_bf16.h>

typedef __attribute__((ext_vector_type(8))) short short8_t;
typedef __attribute__((ext_vector_type(4))) float f32x4;

__device__ __forceinline__ short f2bf(float x){
  union { float f; unsigned u; } v; v.f = x;
  unsigned r = v.u + 0x7fffu + ((v.u >> 16) & 1u);
  return (short)(r >> 16);
}
__device__ __forceinline__ unsigned pack2(float lo, float hi){
  return (unsigned)(unsigned short)f2bf(lo) | ((unsigned)(unsigned short)f2bf(hi) << 16);
}
__device__ __forceinline__ float bf2f(unsigned short u){
  union { unsigned u; float f; } v; v.u = ((unsigned)u) << 16; return v.f;
}

__global__ __launch_bounds__(256) void k_zero_i32(int* __restrict__ p, int n){
  int i = blockIdx.x*256 + threadIdx.x;
  if (i < n) p[i] = 0;
}

__global__ __launch_bounds__(256) void k_hist(const int* __restrict__ ei, int* __restrict__ cnt, int E){
  int i = blockIdx.x*256 + threadIdx.x;
  if (i < E) atomicAdd(&cnt[ei[E + i]], 1);
}

__global__ __launch_bounds__(1024) void k_scan(const int* __restrict__ cnt, int* __restrict__ off,
                                               int* __restrict__ cursor, float* __restrict__ dinv, int N){
  __shared__ int part[1024];
  int t = threadIdx.x;
  int chunk = (N + 1023) >> 10;
  int lo = t*chunk; if (lo > N) lo = N;
  int hi = lo + chunk; if (hi > N) hi = N;
  int s = 0;
  for (int i = lo; i < hi; ++i) s += cnt[i];
  part[t] = s; __syncthreads();
  for (int d = 1; d < 1024; d <<= 1){
    int v = (t >= d) ? part[t-d] : 0;
    __syncthreads();
    part[t] += v;
    __syncthreads();
  }
  int run = (t == 0) ? 0 : part[t-1];
  for (int i = lo; i < hi; ++i){
    off[i] = run; cursor[i] = run;
    dinv[i] = rsqrtf((float)(cnt[i] + 1));
    run += cnt[i];
  }
  if (t == 1023) off[N] = part[1023];
}

__global__ __launch_bounds__(256) void k_scatter(const int* __restrict__ ei, int* __restrict__ cursor,
                                                 int* __restrict__ ebuf, int E){
  int i = blockIdx.x*256 + threadIdx.x;
  if (i < E){
    int s = ei[i], d = ei[E + i];
    int p = atomicAdd(&cursor[d], 1);
    ebuf[p] = s;
  }
}

// W [K x 64] fp32 -> bf16 fragment layout.
__global__ __launch_bounds__(256) void k_wconv(const float* __restrict__ W, short* __restrict__ Wb, int total){
  int tid = blockIdx.x*256 + threadIdx.x;
  if (tid >= total) return;
  int e  = tid & 7;
  int l  = (tid >> 3) & 63;
  int nt = (tid >> 9) & 3;
  int kt = tid >> 11;
  int k  = kt*32 + (l >> 4)*8 + e;
  int col = nt*16 + (l & 15);
  Wb[tid] = f2bf(W[(size_t)k*64 + col]);
}

// GEMM1: LDS-staged coalesced A loads, per-wave private 16-row tile.
__global__ __launch_bounds__(256) void k_gemm1(const float* __restrict__ A, const short* __restrict__ Wb,
                                               const float* __restrict__ dinv, unsigned short* __restrict__ out,
                                               int M){
  __shared__ unsigned short lds[64*256];
  int wid = threadIdx.x >> 6, lane = threadIdx.x & 63;
  int row0 = blockIdx.x*64 + wid*16;
  if (row0 >= M) return;
  int rfrag = lane & 15, g = lane >> 4;
  char* ldsb = (char*)lds;
  const short8_t* wb = (const short8_t*)Wb + lane;
  f32x4 acc0 = {0.f,0.f,0.f,0.f}, acc1 = acc0, acc2 = acc0, acc3 = acc0;

  int wbase = wid*16*512;
  int wsel  = (lane >> 1);
  int whalf = (lane & 1) << 3;

  for (int ko = 0; ko < 8; ++ko){
    #pragma unroll
    for (int r = 0; r < 16; ++r){
      const float4 a = *(const float4*)(A + (size_t)(row0 + r)*2048 + ko*256 + lane*4);
      uint2 p; p.x = pack2(a.x, a.y); p.y = pack2(a.z, a.w);
      *(uint2*)(ldsb + wbase + r*512 + ((wsel ^ (r & 7)) << 4) + whalf) = p;
    }
    asm volatile("s_waitcnt lgkmcnt(0)" ::: "memory");
    #pragma unroll
    for (int kt = 0; kt < 8; ++kt){
      short8_t af = *(const short8_t*)(ldsb + wbase + rfrag*512 + ((((kt<<2) + g) ^ (rfrag & 7)) << 4));
      int ktg = ko*8 + kt;
      short8_t b0 = wb[(ktg*4+0)*64];
      short8_t b1 = wb[(ktg*4+1)*64];
      short8_t b2 = wb[(ktg*4+2)*64];
      short8_t b3 = wb[(ktg*4+3)*64];
      acc0 = __builtin_amdgcn_mfma_f32_16x16x32_bf16(af, b0, acc0, 0,0,0);
      acc1 = __builtin_amdgcn_mfma_f32_16x16x32_bf16(af, b1, acc1, 0,0,0);
      acc2 = __builtin_amdgcn_mfma_f32_16x16x32_bf16(af, b2, acc2, 0,0,0);
      acc3 = __builtin_amdgcn_mfma_f32_16x16x32_bf16(af, b3, acc3, 0,0,0);
    }
  }

  int orow = row0 + g*4;
  float d0 = dinv[orow], d1 = dinv[orow+1], d2 = dinv[orow+2], d3 = dinv[orow+3];
  unsigned short* op = out + (size_t)orow*64 + rfrag;
  op[0*64 +  0] = (unsigned short)f2bf(acc0[0]*d0);
  op[0*64 + 16] = (unsigned short)f2bf(acc1[0]*d0);
  op[0*64 + 32] = (unsigned short)f2bf(acc2[0]*d0);
  op[0*64 + 48] = (unsigned short)f2bf(acc3[0]*d0);
  op[1*64 +  0] = (unsigned short)f2bf(acc0[1]*d1);
  op[1*64 + 16] = (unsigned short)f2bf(acc1[1]*d1);
  op[1*64 + 32] = (unsigned short)f2bf(acc2[1]*d1);
  op[1*64 + 48] = (unsigned short)f2bf(acc3[1]*d1);
  op[2*64 +  0] = (unsigned short)f2bf(acc0[2]*d2);
  op[2*64 + 16] = (unsigned short)f2bf(acc1[2]*d2);
  op[2*64 + 32] = (unsigned short)f2bf(acc2[2]*d2);
  op[2*64 + 48] = (unsigned short)f2bf(acc3[2]*d2);
  op[3*64 +  0] = (unsigned short)f2bf(acc0[3]*d3);
  op[3*64 + 16] = (unsigned short)f2bf(acc1[3]*d3);
  op[3*64 + 32] = (unsigned short)f2bf(acc2[3]*d3);
  op[3*64 + 48] = (unsigned short)f2bf(acc3[3]*d3);
}

template<int KTILES>
__global__ __launch_bounds__(256) void k_gemm_sm(const unsigned short* __restrict__ Ah,
                                                 const short* __restrict__ Wb, const float* __restrict__ dinv,
                                                 unsigned short* __restrict__ out, int M, int lda){
  int wid = threadIdx.x >> 6, lane = threadIdx.x & 63;
  int row0 = (blockIdx.x*4 + wid)*16;
  if (row0 >= M) return;
  int r = lane & 15, g = lane >> 4;
  const short8_t* wb = (const short8_t*)Wb + lane;
  f32x4 acc0 = {0.f,0.f,0.f,0.f}, acc1 = acc0, acc2 = acc0, acc3 = acc0;
  #pragma unroll
  for (int kt = 0; kt < KTILES; ++kt){
    short8_t af = *(const short8_t*)(Ah + (size_t)(row0 + r)*lda + kt*32 + g*8);
    short8_t b0 = wb[(kt*4+0)*64];
    short8_t b1 = wb[(kt*4+1)*64];
    short8_t b2 = wb[(kt*4+2)*64];
    short8_t b3 = wb[(kt*4+3)*64];
    acc0 = __builtin_amdgcn_mfma_f32_16x16x32_bf16(af, b0, acc0, 0,0,0);
    acc1 = __builtin_amdgcn_mfma_f32_16x16x32_bf16(af, b1, acc1, 0,0,0);
    acc2 = __builtin_amdgcn_mfma_f32_16x16x32_bf16(af, b2, acc2, 0,0,0);
    acc3 = __builtin_amdgcn_mfma_f32_16x16x32_bf16(af, b3, acc3, 0,0,0);
  }
  int orow = row0 + g*4;
  float d0 = dinv[orow], d1 = dinv[orow+1], d2 = dinv[orow+2], d3 = dinv[orow+3];
  unsigned short* op = out + (size_t)orow*64 + r;
  op[0*64 +  0] = (unsigned short)f2bf(acc0[0]*d0);
  op[0*64 + 16] = (unsigned short)f2bf(acc1[0]*d0);
  op[0*64 + 32] = (unsigned short)f2bf(acc2[0]*d0);
  op[0*64 + 48] = (unsigned short)f2bf(acc3[0]*d0);
  op[1*64 +  0] = (unsigned short)f2bf(acc0[1]*d1);
  op[1*64 + 16] = (unsigned short)f2bf(acc1[1]*d1);
  op[1*64 + 32] = (unsigned short)f2bf(acc2[1]*d1);
  op[1*64 + 48] = (unsigned short)f2bf(acc3[1]*d1);
  op[2*64 +  0] = (unsigned short)f2bf(acc0[2]*d2);
  op[2*64 + 16] = (unsigned short)f2bf(acc1[2]*d2);
  op[2*64 + 32] = (unsigned short)f2bf(acc2[2]*d2);
  op[2*64 + 48] = (unsigned short)f2bf(acc3[2]*d2);
  op[3*64 +  0] = (unsigned short)f2bf(acc0[3]*d3);
  op[3*64 + 16] = (unsigned short)f2bf(acc1[3]*d3);
  op[3*64 + 32] = (unsigned short)f2bf(acc2[3]*d3);
  op[3*64 + 48] = (unsigned short)f2bf(acc3[3]*d3);
}

template<bool FUSE>
__global__ __launch_bounds__(256) void k_agg(const unsigned short* __restrict__ hin, const int* __restrict__ off,
                                             const int* __restrict__ ebuf, const float* __restrict__ dinv,
                                             const float* __restrict__ bias, void* __restrict__ outp, int N){
  int lane = threadIdx.x & 63, wid = threadIdx.x >> 6;
  float b = bias[lane];
  float fsum = 0.f;
  int stride = gridDim.x*4;
  for (int i = blockIdx.x*4 + wid; i < N; i += stride){
    float acc = bf2f(hin[(size_t)i*64 + lane]);
    int j  = off[i];
    int j1 = off[i+1];
    for (; j + 4 <= j1; j += 4){
      int s0 = ebuf[j], s1 = ebuf[j+1], s2 = ebuf[j+2], s3 = ebuf[j+3];
      acc += bf2f(hin[(size_t)s0*64 + lane]);
      acc += bf2f(hin[(size_t)s1*64 + lane]);
      acc += bf2f(hin[(size_t)s2*64 + lane]);
      acc += bf2f(hin[(size_t)s3*64 + lane]);
    }
    for (; j < j1; ++j){
      int s = ebuf[j];
      acc += bf2f(hin[(size_t)s*64 + lane]);
    }
    float z = fmaxf(dinv[i]*acc + b, 0.f);
    if (FUSE) fsum += z;
    else ((unsigned short*)outp)[(size_t)i*64 + lane] = (unsigned short)f2bf(z);
  }
  if (FUSE){
    __shared__ float sm[4][64];
    sm[wid][lane] = fsum;
    __syncthreads();
    if (wid == 0)
      ((float*)outp)[(size_t)blockIdx.x*64 + lane] = sm[0][lane] + sm[1][lane] + sm[2][lane] + sm[3][lane];
  }
}

__global__ __launch_bounds__(256) void k_final(const float* __restrict__ part, float* __restrict__ out,
                                               int NB, float invN){
  int f = blockIdx.x;
  float s = 0.f;
  for (int b = threadIdx.x; b < NB; b += 256) s += part[(size_t)b*64 + f];
  __shared__ float sm[256];
  sm[threadIdx.x] = s; __syncthreads();
  for (int d = 128; d > 0; d >>= 1){
    if (threadIdx.x < d) sm[threadIdx.x] += sm[threadIdx.x + d];
    __syncthreads();
  }
  if (threadIdx.x == 0) out[f] = sm[0]*invN;
}

extern "C" void kernel_launch(void* const* d_in, const int* in_sizes, int n_in,
                              void* d_out, int out_size, void* d_ws, size_t ws_size,
                              hipStream_t stream){
  const float* x  = (const float*)d_in[0];
  const int*   ei = (const int*)d_in[1];
  const float* W1 = (const float*)d_in[2];
  const float* b1 = (const float*)d_in[3];
  const float* W2 = (const float*)d_in[4];
  const float* b2 = (const float*)d_in[5];
  float* out = (float*)d_out;

  const int IN = 2048;
  int N = in_sizes[0] / IN;      // 50000
  int E = in_sizes[1] / 2;       // 1.6M

  char* w = (char*)d_ws;
  auto alloc = [&](size_t bytes){ char* p = w; w += (bytes + 255) & ~255ULL; return (void*)p; };
  int*   cnt    = (int*)  alloc((size_t)N*4);
  int*   off    = (int*)  alloc((size_t)(N+1)*4);
  int*   cursor = (int*)  alloc((size_t)N*4);
  float* dinv   = (float*)alloc((size_t)N*4);
  int*   ebuf   = (int*)  alloc((size_t)E*4);
  short* Wb1    = (short*)alloc((size_t)64*2048*2);
  short* Wb2    = (short*)alloc((size_t)2*2048*2);
  unsigned short* h1 = (unsigned short*)alloc((size_t)N*64*2);
  unsigned short* z1 = (unsigned short*)alloc((size_t)N*64*2);
  const int NB2 = 2048;
  float* part   = (float*)alloc((size_t)NB2*64*4);

  int eb = (E + 255)/256;
  k_zero_i32<<<(N+255)/256, 256, 0, stream>>>(cnt, N);
  k_hist   <<<eb, 256, 0, stream>>>(ei, cnt, E);
  k_scan   <<<1, 1024, 0, stream>>>(cnt, off, cursor, dinv, N);
  k_scatter<<<eb, 256, 0, stream>>>(ei, cursor, ebuf, E);
  k_wconv  <<<(64*2048 + 255)/256, 256, 0, stream>>>(W1, Wb1, 64*2048);
  k_wconv  <<<(2*2048  + 255)/256, 256, 0, stream>>>(W2, Wb2, 2*2048);

  int b1blocks = (N + 63)/64;
  int smblocks = ((N + 15)/16 + 3)/4;
  // --- PROBE: gemm1 x3 (idempotent). dur_delta vs R3(581) = 2*(G1 + ovh) ---
  k_gemm1<<<b1blocks, 256, 0, stream>>>(x, Wb1, dinv, h1, N);
  k_gemm1<<<b1blocks, 256, 0, stream>>>(x, Wb1, dinv, h1, N);
  k_gemm1<<<b1blocks, 256, 0, stream>>>(x, Wb1, dinv, h1, N);
  k_agg<false><<<NB2, 256, 0, stream>>>(h1, off, ebuf, dinv, b1, (void*)z1, N);
  k_gemm_sm<2><<<smblocks, 256, 0, stream>>>(z1, Wb2, dinv, h1, N, 64);
  k_agg<true> <<<NB2, 256, 0, stream>>>(h1, off, ebuf, dinv, b2, (void*)part, N);
  k_final  <<<64, 256, 0, stream>>>(part, out, NB2, 1.0f/(float)N);
}

// Round 6
// 450.433 us; speedup vs baseline: 1.8138x; 1.8138x over previous
//
#include <hip/hip_runtime.h>
#include <hip/hip_bf16.h>

typedef __attribute__((ext_vector_type(8))) short short8_t;
typedef __attribute__((ext_vector_type(4))) float f32x4;

__device__ __forceinline__ short f2bf(float x){
  union { float f; unsigned u; } v; v.f = x;
  unsigned r = v.u + 0x7fffu + ((v.u >> 16) & 1u);
  return (short)(r >> 16);
}
__device__ __forceinline__ unsigned pack2(float lo, float hi){
  return (unsigned)(unsigned short)f2bf(lo) | ((unsigned)(unsigned short)f2bf(hi) << 16);
}
__device__ __forceinline__ float bf2f(unsigned short u){
  union { unsigned u; float f; } v; v.u = ((unsigned)u) << 16; return v.f;
}

__global__ __launch_bounds__(256) void k_hist(const int* __restrict__ ei, int* __restrict__ cnt, int E){
  int i = blockIdx.x*256 + threadIdx.x;
  if (i < E) atomicAdd(&cnt[ei[E + i]], 1);
}

// ---- parallel scan: 256 partials, then per-block rescan ----
__global__ __launch_bounds__(256) void k_part(const int* __restrict__ cnt, int* __restrict__ partial, int N){
  int b = blockIdx.x, t = threadIdx.x;
  int chunk = (N + 255) >> 8;
  int lo = b*chunk, hi = lo + chunk; if (hi > N) hi = N;
  int s = 0;
  for (int i = lo + t; i < hi; i += 256) s += cnt[i];
  __shared__ int sm[256];
  sm[t] = s; __syncthreads();
  for (int d = 128; d; d >>= 1){ if (t < d) sm[t] += sm[t+d]; __syncthreads(); }
  if (t == 0) partial[b] = sm[0];
}

__global__ __launch_bounds__(256) void k_scan2(const int* __restrict__ cnt, const int* __restrict__ partial,
                                               int* __restrict__ off, int* __restrict__ cursor,
                                               float* __restrict__ dinv, int N){
  int b = blockIdx.x, t = threadIdx.x;
  __shared__ int ps[256];
  ps[t] = partial[t]; __syncthreads();
  for (int d = 1; d < 256; d <<= 1){
    int v = (t >= d) ? ps[t-d] : 0; __syncthreads(); ps[t] += v; __syncthreads();
  }
  int base  = b ? ps[b-1] : 0;
  int total = ps[255];
  int chunk = (N + 255) >> 8;
  int lo = b*chunk, hi = lo + chunk; if (hi > N) hi = N;
  __shared__ int vs[256];
  int run = base;
  for (int j0 = lo; j0 < hi; j0 += 256){
    int i = j0 + t;
    int c = (i < hi) ? cnt[i] : 0;
    vs[t] = c; __syncthreads();
    for (int d = 1; d < 256; d <<= 1){
      int v = (t >= d) ? vs[t-d] : 0; __syncthreads(); vs[t] += v; __syncthreads();
    }
    if (i < hi){
      int excl = run + vs[t] - c;
      off[i] = excl; cursor[i] = excl;
      dinv[i] = rsqrtf((float)(c + 1));
    }
    run += vs[255];
    __syncthreads();
  }
  if (b == 255 && t == 0) off[N] = total;
}

__global__ __launch_bounds__(256) void k_scatter(const int* __restrict__ ei, int* __restrict__ cursor,
                                                 int* __restrict__ ebuf, int E){
  int i = blockIdx.x*256 + threadIdx.x;
  if (i < E){
    int s = ei[i], d = ei[E + i];
    int p = atomicAdd(&cursor[d], 1);
    ebuf[p] = s;
  }
}

// Both W -> bf16 fragment layouts in one launch.
__global__ __launch_bounds__(256) void k_wconv2(const float* __restrict__ W1, short* __restrict__ Wb1,
                                                const float* __restrict__ W2, short* __restrict__ Wb2){
  int tid = blockIdx.x*256 + threadIdx.x;
  const float* W; short* Wb; int t;
  if (tid < 64*2048){ W = W1; Wb = Wb1; t = tid; }
  else if (tid < 64*2048 + 2*2048){ W = W2; Wb = Wb2; t = tid - 64*2048; }
  else return;
  int e  = t & 7;
  int l  = (t >> 3) & 63;
  int nt = (t >> 9) & 3;
  int kt = t >> 11;
  int k  = kt*32 + (l >> 4)*8 + e;
  int col = nt*16 + (l & 15);
  Wb[t] = f2bf(W[(size_t)k*64 + col]);
}

// GEMM1: LDS-staged coalesced A loads, per-wave private 16-row tile.
__global__ __launch_bounds__(256) void k_gemm1(const float* __restrict__ A, const short* __restrict__ Wb,
                                               const float* __restrict__ dinv, unsigned short* __restrict__ out,
                                               int M){
  __shared__ unsigned short lds[64*256];
  int wid = threadIdx.x >> 6, lane = threadIdx.x & 63;
  int row0 = blockIdx.x*64 + wid*16;
  if (row0 >= M) return;
  int rfrag = lane & 15, g = lane >> 4;
  char* ldsb = (char*)lds;
  const short8_t* wb = (const short8_t*)Wb + lane;
  f32x4 acc0 = {0.f,0.f,0.f,0.f}, acc1 = acc0, acc2 = acc0, acc3 = acc0;

  int wbase = wid*16*512;
  int wsel  = (lane >> 1);
  int whalf = (lane & 1) << 3;

  for (int ko = 0; ko < 8; ++ko){
    #pragma unroll
    for (int r = 0; r < 16; ++r){
      const float4 a = *(const float4*)(A + (size_t)(row0 + r)*2048 + ko*256 + lane*4);
      uint2 p; p.x = pack2(a.x, a.y); p.y = pack2(a.z, a.w);
      *(uint2*)(ldsb + wbase + r*512 + ((wsel ^ (r & 7)) << 4) + whalf) = p;
    }
    asm volatile("s_waitcnt lgkmcnt(0)" ::: "memory");
    #pragma unroll
    for (int kt = 0; kt < 8; ++kt){
      short8_t af = *(const short8_t*)(ldsb + wbase + rfrag*512 + ((((kt<<2) + g) ^ (rfrag & 7)) << 4));
      int ktg = ko*8 + kt;
      short8_t b0 = wb[(ktg*4+0)*64];
      short8_t b1 = wb[(ktg*4+1)*64];
      short8_t b2 = wb[(ktg*4+2)*64];
      short8_t b3 = wb[(ktg*4+3)*64];
      acc0 = __builtin_amdgcn_mfma_f32_16x16x32_bf16(af, b0, acc0, 0,0,0);
      acc1 = __builtin_amdgcn_mfma_f32_16x16x32_bf16(af, b1, acc1, 0,0,0);
      acc2 = __builtin_amdgcn_mfma_f32_16x16x32_bf16(af, b2, acc2, 0,0,0);
      acc3 = __builtin_amdgcn_mfma_f32_16x16x32_bf16(af, b3, acc3, 0,0,0);
    }
  }

  int orow = row0 + g*4;
  float d0 = dinv[orow], d1 = dinv[orow+1], d2 = dinv[orow+2], d3 = dinv[orow+3];
  unsigned short* op = out + (size_t)orow*64 + rfrag;
  op[0*64 +  0] = (unsigned short)f2bf(acc0[0]*d0);
  op[0*64 + 16] = (unsigned short)f2bf(acc1[0]*d0);
  op[0*64 + 32] = (unsigned short)f2bf(acc2[0]*d0);
  op[0*64 + 48] = (unsigned short)f2bf(acc3[0]*d0);
  op[1*64 +  0] = (unsigned short)f2bf(acc0[1]*d1);
  op[1*64 + 16] = (unsigned short)f2bf(acc1[1]*d1);
  op[1*64 + 32] = (unsigned short)f2bf(acc2[1]*d1);
  op[1*64 + 48] = (unsigned short)f2bf(acc3[1]*d1);
  op[2*64 +  0] = (unsigned short)f2bf(acc0[2]*d2);
  op[2*64 + 16] = (unsigned short)f2bf(acc1[2]*d2);
  op[2*64 + 32] = (unsigned short)f2bf(acc2[2]*d2);
  op[2*64 + 48] = (unsigned short)f2bf(acc3[2]*d2);
  op[3*64 +  0] = (unsigned short)f2bf(acc0[3]*d3);
  op[3*64 + 16] = (unsigned short)f2bf(acc1[3]*d3);
  op[3*64 + 32] = (unsigned short)f2bf(acc2[3]*d3);
  op[3*64 + 48] = (unsigned short)f2bf(acc3[3]*d3);
}

template<int KTILES>
__global__ __launch_bounds__(256) void k_gemm_sm(const unsigned short* __restrict__ Ah,
                                                 const short* __restrict__ Wb, const float* __restrict__ dinv,
                                                 unsigned short* __restrict__ out, int M, int lda){
  int wid = threadIdx.x >> 6, lane = threadIdx.x & 63;
  int row0 = (blockIdx.x*4 + wid)*16;
  if (row0 >= M) return;
  int r = lane & 15, g = lane >> 4;
  const short8_t* wb = (const short8_t*)Wb + lane;
  f32x4 acc0 = {0.f,0.f,0.f,0.f}, acc1 = acc0, acc2 = acc0, acc3 = acc0;
  #pragma unroll
  for (int kt = 0; kt < KTILES; ++kt){
    short8_t af = *(const short8_t*)(Ah + (size_t)(row0 + r)*lda + kt*32 + g*8);
    short8_t b0 = wb[(kt*4+0)*64];
    short8_t b1 = wb[(kt*4+1)*64];
    short8_t b2 = wb[(kt*4+2)*64];
    short8_t b3 = wb[(kt*4+3)*64];
    acc0 = __builtin_amdgcn_mfma_f32_16x16x32_bf16(af, b0, acc0, 0,0,0);
    acc1 = __builtin_amdgcn_mfma_f32_16x16x32_bf16(af, b1, acc1, 0,0,0);
    acc2 = __builtin_amdgcn_mfma_f32_16x16x32_bf16(af, b2, acc2, 0,0,0);
    acc3 = __builtin_amdgcn_mfma_f32_16x16x32_bf16(af, b3, acc3, 0,0,0);
  }
  int orow = row0 + g*4;
  float d0 = dinv[orow], d1 = dinv[orow+1], d2 = dinv[orow+2], d3 = dinv[orow+3];
  unsigned short* op = out + (size_t)orow*64 + r;
  op[0*64 +  0] = (unsigned short)f2bf(acc0[0]*d0);
  op[0*64 + 16] = (unsigned short)f2bf(acc1[0]*d0);
  op[0*64 + 32] = (unsigned short)f2bf(acc2[0]*d0);
  op[0*64 + 48] = (unsigned short)f2bf(acc3[0]*d0);
  op[1*64 +  0] = (unsigned short)f2bf(acc0[1]*d1);
  op[1*64 + 16] = (unsigned short)f2bf(acc1[1]*d1);
  op[1*64 + 32] = (unsigned short)f2bf(acc2[1]*d1);
  op[1*64 + 48] = (unsigned short)f2bf(acc3[1]*d1);
  op[2*64 +  0] = (unsigned short)f2bf(acc0[2]*d2);
  op[2*64 + 16] = (unsigned short)f2bf(acc1[2]*d2);
  op[2*64 + 32] = (unsigned short)f2bf(acc2[2]*d2);
  op[2*64 + 48] = (unsigned short)f2bf(acc3[2]*d2);
  op[3*64 +  0] = (unsigned short)f2bf(acc0[3]*d3);
  op[3*64 + 16] = (unsigned short)f2bf(acc1[3]*d3);
  op[3*64 + 32] = (unsigned short)f2bf(acc2[3]*d3);
  op[3*64 + 48] = (unsigned short)f2bf(acc3[3]*d3);
}

template<bool FUSE>
__global__ __launch_bounds__(256) void k_agg(const unsigned short* __restrict__ hin, const int* __restrict__ off,
                                             const int* __restrict__ ebuf, const float* __restrict__ dinv,
                                             const float* __restrict__ bias, void* __restrict__ outp, int N){
  int lane = threadIdx.x & 63, wid = threadIdx.x >> 6;
  float b = bias[lane];
  float fsum = 0.f;
  int stride = gridDim.x*4;
  for (int i = blockIdx.x*4 + wid; i < N; i += stride){
    float acc = bf2f(hin[(size_t)i*64 + lane]);
    int j  = off[i];
    int j1 = off[i+1];
    for (; j + 4 <= j1; j += 4){
      int s0 = ebuf[j], s1 = ebuf[j+1], s2 = ebuf[j+2], s3 = ebuf[j+3];
      acc += bf2f(hin[(size_t)s0*64 + lane]);
      acc += bf2f(hin[(size_t)s1*64 + lane]);
      acc += bf2f(hin[(size_t)s2*64 + lane]);
      acc += bf2f(hin[(size_t)s3*64 + lane]);
    }
    for (; j < j1; ++j){
      int s = ebuf[j];
      acc += bf2f(hin[(size_t)s*64 + lane]);
    }
    float z = fmaxf(dinv[i]*acc + b, 0.f);
    if (FUSE) fsum += z;
    else ((unsigned short*)outp)[(size_t)i*64 + lane] = (unsigned short)f2bf(z);
  }
  if (FUSE){
    __shared__ float sm[4][64];
    sm[wid][lane] = fsum;
    __syncthreads();
    if (wid == 0)
      ((float*)outp)[(size_t)blockIdx.x*64 + lane] = sm[0][lane] + sm[1][lane] + sm[2][lane] + sm[3][lane];
  }
}

__global__ __launch_bounds__(256) void k_final(const float* __restrict__ part, float* __restrict__ out,
                                               int NB, float invN){
  int f = blockIdx.x;
  float s = 0.f;
  for (int b = threadIdx.x; b < NB; b += 256) s += part[(size_t)b*64 + f];
  __shared__ float sm[256];
  sm[threadIdx.x] = s; __syncthreads();
  for (int d = 128; d > 0; d >>= 1){
    if (threadIdx.x < d) sm[threadIdx.x] += sm[threadIdx.x + d];
    __syncthreads();
  }
  if (threadIdx.x == 0) out[f] = sm[0]*invN;
}

extern "C" void kernel_launch(void* const* d_in, const int* in_sizes, int n_in,
                              void* d_out, int out_size, void* d_ws, size_t ws_size,
                              hipStream_t stream){
  const float* x  = (const float*)d_in[0];
  const int*   ei = (const int*)d_in[1];
  const float* W1 = (const float*)d_in[2];
  const float* b1 = (const float*)d_in[3];
  const float* W2 = (const float*)d_in[4];
  const float* b2 = (const float*)d_in[5];
  float* out = (float*)d_out;

  const int IN = 2048;
  int N = in_sizes[0] / IN;      // 50000
  int E = in_sizes[1] / 2;       // 1.6M

  char* w = (char*)d_ws;
  auto alloc = [&](size_t bytes){ char* p = w; w += (bytes + 255) & ~255ULL; return (void*)p; };
  int*   cnt     = (int*)  alloc((size_t)N*4);
  int*   off     = (int*)  alloc((size_t)(N+1)*4);
  int*   cursor  = (int*)  alloc((size_t)N*4);
  float* dinv    = (float*)alloc((size_t)N*4);
  int*   partial = (int*)  alloc(256*4);
  int*   ebuf    = (int*)  alloc((size_t)E*4);
  short* Wb1     = (short*)alloc((size_t)64*2048*2);
  short* Wb2     = (short*)alloc((size_t)2*2048*2);
  unsigned short* h1 = (unsigned short*)alloc((size_t)N*64*2);
  unsigned short* z1 = (unsigned short*)alloc((size_t)N*64*2);
  const int NB2 = 2048;
  float* part    = (float*)alloc((size_t)NB2*64*4);

  int eb = (E + 255)/256;
  hipMemsetAsync(cnt, 0, (size_t)N*4, stream);
  k_hist   <<<eb, 256, 0, stream>>>(ei, cnt, E);
  k_part   <<<256, 256, 0, stream>>>(cnt, partial, N);
  k_scan2  <<<256, 256, 0, stream>>>(cnt, partial, off, cursor, dinv, N);
  k_scatter<<<eb, 256, 0, stream>>>(ei, cursor, ebuf, E);
  k_wconv2 <<<(64*2048 + 2*2048 + 255)/256, 256, 0, stream>>>(W1, Wb1, W2, Wb2);

  int b1blocks = (N + 63)/64;
  int smblocks = ((N + 15)/16 + 3)/4;
  k_gemm1<<<b1blocks, 256, 0, stream>>>(x, Wb1, dinv, h1, N);
  k_agg<false><<<NB2, 256, 0, stream>>>(h1, off, ebuf, dinv, b1, (void*)z1, N);
  k_gemm_sm<2><<<smblocks, 256, 0, stream>>>(z1, Wb2, dinv, h1, N, 64);
  k_agg<true> <<<NB2, 256, 0, stream>>>(h1, off, ebuf, dinv, b2, (void*)part, N);
  k_final  <<<64, 256, 0, stream>>>(part, out, NB2, 1.0f/(float)N);
}

// Round 7
// 366.633 us; speedup vs baseline: 2.2283x; 1.2286x over previous
//
#include <hip/hip_runtime.h>
#include <hip/hip_bf16.h>

typedef __attribute__((ext_vector_type(8))) short short8_t;
typedef __attribute__((ext_vector_type(4))) float f32x4;

__device__ __forceinline__ short f2bf(float x){
  union { float f; unsigned u; } v; v.f = x;
  unsigned r = v.u + 0x7fffu + ((v.u >> 16) & 1u);
  return (short)(r >> 16);
}
__device__ __forceinline__ unsigned pack2(float lo, float hi){
  return (unsigned)(unsigned short)f2bf(lo) | ((unsigned)(unsigned short)f2bf(hi) << 16);
}
__device__ __forceinline__ float bf2f(unsigned short u){
  union { unsigned u; float f; } v; v.u = ((unsigned)u) << 16; return v.f;
}

// Both W -> bf16 fragment layouts in one launch.
__global__ __launch_bounds__(256) void k_wconv2(const float* __restrict__ W1, short* __restrict__ Wb1,
                                                const float* __restrict__ W2, short* __restrict__ Wb2){
  int tid = blockIdx.x*256 + threadIdx.x;
  const float* W; short* Wb; int t;
  if (tid < 64*2048){ W = W1; Wb = Wb1; t = tid; }
  else if (tid < 64*2048 + 2*2048){ W = W2; Wb = Wb2; t = tid - 64*2048; }
  else return;
  int e  = t & 7;
  int l  = (t >> 3) & 63;
  int nt = (t >> 9) & 3;
  int kt = t >> 11;
  int k  = kt*32 + (l >> 4)*8 + e;
  int col = nt*16 + (l & 15);
  Wb[t] = f2bf(W[(size_t)k*64 + col]);
}

// FUSED-1: blocks [0,EB) = histogram + per-edge rank; blocks [EB,EB+GB) = GEMM1 -> fp32 unscaled h1raw.
__global__ __launch_bounds__(256) void k_hist_gemm1(const int* __restrict__ ei, int* __restrict__ cnt,
                                                    int* __restrict__ rank, int E,
                                                    const float* __restrict__ A, const short* __restrict__ Wb,
                                                    float* __restrict__ h1raw, int M, int EB){
  __shared__ unsigned short lds[64*256];
  if ((int)blockIdx.x < EB){
    int i = blockIdx.x*256 + threadIdx.x;
    if (i < E) rank[i] = atomicAdd(&cnt[ei[E + i]], 1);
    return;
  }
  int wid = threadIdx.x >> 6, lane = threadIdx.x & 63;
  int row0 = (blockIdx.x - EB)*64 + wid*16;
  if (row0 >= M) return;
  int rfrag = lane & 15, g = lane >> 4;
  char* ldsb = (char*)lds;
  const short8_t* wb = (const short8_t*)Wb + lane;
  f32x4 acc0 = {0.f,0.f,0.f,0.f}, acc1 = acc0, acc2 = acc0, acc3 = acc0;

  int wbase = wid*16*512;
  int wsel  = (lane >> 1);
  int whalf = (lane & 1) << 3;

  for (int ko = 0; ko < 8; ++ko){
    #pragma unroll
    for (int r = 0; r < 16; ++r){
      const float4 a = *(const float4*)(A + (size_t)(row0 + r)*2048 + ko*256 + lane*4);
      uint2 p; p.x = pack2(a.x, a.y); p.y = pack2(a.z, a.w);
      *(uint2*)(ldsb + wbase + r*512 + ((wsel ^ (r & 7)) << 4) + whalf) = p;
    }
    asm volatile("s_waitcnt lgkmcnt(0)" ::: "memory");
    #pragma unroll
    for (int kt = 0; kt < 8; ++kt){
      short8_t af = *(const short8_t*)(ldsb + wbase + rfrag*512 + ((((kt<<2) + g) ^ (rfrag & 7)) << 4));
      int ktg = ko*8 + kt;
      short8_t b0 = wb[(ktg*4+0)*64];
      short8_t b1 = wb[(ktg*4+1)*64];
      short8_t b2 = wb[(ktg*4+2)*64];
      short8_t b3 = wb[(ktg*4+3)*64];
      acc0 = __builtin_amdgcn_mfma_f32_16x16x32_bf16(af, b0, acc0, 0,0,0);
      acc1 = __builtin_amdgcn_mfma_f32_16x16x32_bf16(af, b1, acc1, 0,0,0);
      acc2 = __builtin_amdgcn_mfma_f32_16x16x32_bf16(af, b2, acc2, 0,0,0);
      acc3 = __builtin_amdgcn_mfma_f32_16x16x32_bf16(af, b3, acc3, 0,0,0);
    }
  }

  int orow = row0 + g*4;
  float* op = h1raw + (size_t)orow*64 + rfrag;
  #pragma unroll
  for (int reg = 0; reg < 4; ++reg){
    op[reg*64 +  0] = acc0[reg];
    op[reg*64 + 16] = acc1[reg];
    op[reg*64 + 32] = acc2[reg];
    op[reg*64 + 48] = acc3[reg];
  }
}

// ---- parallel scan ----
__global__ __launch_bounds__(256) void k_part(const int* __restrict__ cnt, int* __restrict__ partial, int N){
  int b = blockIdx.x, t = threadIdx.x;
  int chunk = (N + 255) >> 8;
  int lo = b*chunk, hi = lo + chunk; if (hi > N) hi = N;
  int s = 0;
  for (int i = lo + t; i < hi; i += 256) s += cnt[i];
  __shared__ int sm[256];
  sm[t] = s; __syncthreads();
  for (int d = 128; d; d >>= 1){ if (t < d) sm[t] += sm[t+d]; __syncthreads(); }
  if (t == 0) partial[b] = sm[0];
}

__global__ __launch_bounds__(256) void k_scan2(const int* __restrict__ cnt, const int* __restrict__ partial,
                                               int* __restrict__ off, float* __restrict__ dinv, int N){
  int b = blockIdx.x, t = threadIdx.x;
  __shared__ int ps[256];
  ps[t] = partial[t]; __syncthreads();
  for (int d = 1; d < 256; d <<= 1){
    int v = (t >= d) ? ps[t-d] : 0; __syncthreads(); ps[t] += v; __syncthreads();
  }
  int base  = b ? ps[b-1] : 0;
  int total = ps[255];
  int chunk = (N + 255) >> 8;
  int lo = b*chunk, hi = lo + chunk; if (hi > N) hi = N;
  __shared__ int vs[256];
  int run = base;
  for (int j0 = lo; j0 < hi; j0 += 256){
    int i = j0 + t;
    int c = (i < hi) ? cnt[i] : 0;
    vs[t] = c; __syncthreads();
    for (int d = 1; d < 256; d <<= 1){
      int v = (t >= d) ? vs[t-d] : 0; __syncthreads(); vs[t] += v; __syncthreads();
    }
    if (i < hi){
      off[i] = run + vs[t] - c;
      dinv[i] = rsqrtf((float)(c + 1));
    }
    run += vs[255];
    __syncthreads();
  }
  if (b == 255 && t == 0) off[N] = total;
}

// FUSED-2: blocks [0,EB) = atomic-free scatter; blocks [EB,EB+SB) = scale h1raw*dinv -> bf16 h1.
__global__ __launch_bounds__(256) void k_scatter_scale(const int* __restrict__ ei, const int* __restrict__ off,
                                                       const int* __restrict__ rank, int* __restrict__ ebuf, int E,
                                                       const float* __restrict__ h1raw, const float* __restrict__ dinv,
                                                       unsigned short* __restrict__ h1, int total8, int EB){
  if ((int)blockIdx.x < EB){
    int i = blockIdx.x*256 + threadIdx.x;
    if (i < E){
      int s = ei[i], d = ei[E + i];
      ebuf[off[d] + rank[i]] = s;
    }
    return;
  }
  int t = (blockIdx.x - EB)*256 + threadIdx.x;
  if (t >= total8) return;
  int base = t*8;
  float dv = dinv[base >> 6];
  const float4 a0 = *(const float4*)(h1raw + base);
  const float4 a1 = *(const float4*)(h1raw + base + 4);
  short8_t o;
  o[0]=f2bf(a0.x*dv); o[1]=f2bf(a0.y*dv); o[2]=f2bf(a0.z*dv); o[3]=f2bf(a0.w*dv);
  o[4]=f2bf(a1.x*dv); o[5]=f2bf(a1.y*dv); o[6]=f2bf(a1.z*dv); o[7]=f2bf(a1.w*dv);
  *(short8_t*)(h1 + base) = o;
}

// GEMM2 (K=64): bf16 A, dinv-scaled epilogue.
template<int KTILES>
__global__ __launch_bounds__(256) void k_gemm_sm(const unsigned short* __restrict__ Ah,
                                                 const short* __restrict__ Wb, const float* __restrict__ dinv,
                                                 unsigned short* __restrict__ out, int M, int lda){
  int wid = threadIdx.x >> 6, lane = threadIdx.x & 63;
  int row0 = (blockIdx.x*4 + wid)*16;
  if (row0 >= M) return;
  int r = lane & 15, g = lane >> 4;
  const short8_t* wb = (const short8_t*)Wb + lane;
  f32x4 acc0 = {0.f,0.f,0.f,0.f}, acc1 = acc0, acc2 = acc0, acc3 = acc0;
  #pragma unroll
  for (int kt = 0; kt < KTILES; ++kt){
    short8_t af = *(const short8_t*)(Ah + (size_t)(row0 + r)*lda + kt*32 + g*8);
    short8_t b0 = wb[(kt*4+0)*64];
    short8_t b1 = wb[(kt*4+1)*64];
    short8_t b2 = wb[(kt*4+2)*64];
    short8_t b3 = wb[(kt*4+3)*64];
    acc0 = __builtin_amdgcn_mfma_f32_16x16x32_bf16(af, b0, acc0, 0,0,0);
    acc1 = __builtin_amdgcn_mfma_f32_16x16x32_bf16(af, b1, acc1, 0,0,0);
    acc2 = __builtin_amdgcn_mfma_f32_16x16x32_bf16(af, b2, acc2, 0,0,0);
    acc3 = __builtin_amdgcn_mfma_f32_16x16x32_bf16(af, b3, acc3, 0,0,0);
  }
  int orow = row0 + g*4;
  float d0 = dinv[orow], d1 = dinv[orow+1], d2 = dinv[orow+2], d3 = dinv[orow+3];
  unsigned short* op = out + (size_t)orow*64 + r;
  op[0*64 +  0] = (unsigned short)f2bf(acc0[0]*d0);
  op[0*64 + 16] = (unsigned short)f2bf(acc1[0]*d0);
  op[0*64 + 32] = (unsigned short)f2bf(acc2[0]*d0);
  op[0*64 + 48] = (unsigned short)f2bf(acc3[0]*d0);
  op[1*64 +  0] = (unsigned short)f2bf(acc0[1]*d1);
  op[1*64 + 16] = (unsigned short)f2bf(acc1[1]*d1);
  op[1*64 + 32] = (unsigned short)f2bf(acc2[1]*d1);
  op[1*64 + 48] = (unsigned short)f2bf(acc3[1]*d1);
  op[2*64 +  0] = (unsigned short)f2bf(acc0[2]*d2);
  op[2*64 + 16] = (unsigned short)f2bf(acc1[2]*d2);
  op[2*64 + 32] = (unsigned short)f2bf(acc2[2]*d2);
  op[2*64 + 48] = (unsigned short)f2bf(acc3[2]*d2);
  op[3*64 +  0] = (unsigned short)f2bf(acc0[3]*d3);
  op[3*64 + 16] = (unsigned short)f2bf(acc1[3]*d3);
  op[3*64 + 32] = (unsigned short)f2bf(acc2[3]*d3);
  op[3*64 + 48] = (unsigned short)f2bf(acc3[3]*d3);
}

template<bool FUSE>
__global__ __launch_bounds__(256) void k_agg(const unsigned short* __restrict__ hin, const int* __restrict__ off,
                                             const int* __restrict__ ebuf, const float* __restrict__ dinv,
                                             const float* __restrict__ bias, void* __restrict__ outp, int N){
  int lane = threadIdx.x & 63, wid = threadIdx.x >> 6;
  float b = bias[lane];
  float fsum = 0.f;
  int stride = gridDim.x*4;
  for (int i = blockIdx.x*4 + wid; i < N; i += stride){
    float acc = bf2f(hin[(size_t)i*64 + lane]);
    int j  = off[i];
    int j1 = off[i+1];
    for (; j + 4 <= j1; j += 4){
      int s0 = ebuf[j], s1 = ebuf[j+1], s2 = ebuf[j+2], s3 = ebuf[j+3];
      acc += bf2f(hin[(size_t)s0*64 + lane]);
      acc += bf2f(hin[(size_t)s1*64 + lane]);
      acc += bf2f(hin[(size_t)s2*64 + lane]);
      acc += bf2f(hin[(size_t)s3*64 + lane]);
    }
    for (; j < j1; ++j){
      int s = ebuf[j];
      acc += bf2f(hin[(size_t)s*64 + lane]);
    }
    float z = fmaxf(dinv[i]*acc + b, 0.f);
    if (FUSE) fsum += z;
    else ((unsigned short*)outp)[(size_t)i*64 + lane] = (unsigned short)f2bf(z);
  }
  if (FUSE){
    __shared__ float sm[4][64];
    sm[wid][lane] = fsum;
    __syncthreads();
    if (wid == 0)
      ((float*)outp)[(size_t)blockIdx.x*64 + lane] = sm[0][lane] + sm[1][lane] + sm[2][lane] + sm[3][lane];
  }
}

__global__ __launch_bounds__(256) void k_final(const float* __restrict__ part, float* __restrict__ out,
                                               int NB, float invN){
  int f = blockIdx.x;
  float s = 0.f;
  for (int b = threadIdx.x; b < NB; b += 256) s += part[(size_t)b*64 + f];
  __shared__ float sm[256];
  sm[threadIdx.x] = s; __syncthreads();
  for (int d = 128; d > 0; d >>= 1){
    if (threadIdx.x < d) sm[threadIdx.x] += sm[threadIdx.x + d];
    __syncthreads();
  }
  if (threadIdx.x == 0) out[f] = sm[0]*invN;
}

extern "C" void kernel_launch(void* const* d_in, const int* in_sizes, int n_in,
                              void* d_out, int out_size, void* d_ws, size_t ws_size,
                              hipStream_t stream){
  const float* x  = (const float*)d_in[0];
  const int*   ei = (const int*)d_in[1];
  const float* W1 = (const float*)d_in[2];
  const float* b1 = (const float*)d_in[3];
  const float* W2 = (const float*)d_in[4];
  const float* b2 = (const float*)d_in[5];
  float* out = (float*)d_out;

  const int IN = 2048;
  int N = in_sizes[0] / IN;      // 50000
  int E = in_sizes[1] / 2;       // 1.6M

  char* w = (char*)d_ws;
  auto alloc = [&](size_t bytes){ char* p = w; w += (bytes + 255) & ~255ULL; return (void*)p; };
  int*   cnt     = (int*)  alloc((size_t)N*4);
  int*   off     = (int*)  alloc((size_t)(N+1)*4);
  float* dinv    = (float*)alloc((size_t)N*4);
  int*   partial = (int*)  alloc(256*4);
  int*   rank    = (int*)  alloc((size_t)E*4);
  int*   ebuf    = (int*)  alloc((size_t)E*4);
  short* Wb1     = (short*)alloc((size_t)64*2048*2);
  short* Wb2     = (short*)alloc((size_t)2*2048*2);
  float* h1raw   = (float*)alloc((size_t)N*64*4);
  unsigned short* h1 = (unsigned short*)alloc((size_t)N*64*2);
  unsigned short* z1 = (unsigned short*)alloc((size_t)N*64*2);
  const int NB2 = 2048;
  float* part    = (float*)alloc((size_t)NB2*64*4);

  int EB = (E + 255)/256;            // 6250
  int GB = (N + 63)/64;              // 782
  int total8 = N*8;                  // N*64/8 scale threads
  int SB = (total8 + 255)/256;       // 1563
  int smblocks = ((N + 15)/16 + 3)/4;

  hipMemsetAsync(cnt, 0, (size_t)N*4, stream);
  k_wconv2 <<<(64*2048 + 2*2048 + 255)/256, 256, 0, stream>>>(W1, Wb1, W2, Wb2);
  k_hist_gemm1<<<EB + GB, 256, 0, stream>>>(ei, cnt, rank, E, x, Wb1, h1raw, N, EB);
  k_part   <<<256, 256, 0, stream>>>(cnt, partial, N);
  k_scan2  <<<256, 256, 0, stream>>>(cnt, partial, off, dinv, N);
  k_scatter_scale<<<EB + SB, 256, 0, stream>>>(ei, off, rank, ebuf, E, h1raw, dinv, h1, total8, EB);
  k_agg<false><<<NB2, 256, 0, stream>>>(h1, off, ebuf, dinv, b1, (void*)z1, N);
  k_gemm_sm<2><<<smblocks, 256, 0, stream>>>(z1, Wb2, dinv, h1, N, 64);
  k_agg<true> <<<NB2, 256, 0, stream>>>(h1, off, ebuf, dinv, b2, (void*)part, N);
  k_final  <<<64, 256, 0, stream>>>(part, out, NB2, 1.0f/(float)N);
}